// Round 1
// baseline (462.932 us; speedup 1.0000x reference)
//
#include <hip/hip_runtime.h>
#include <stdint.h>

#define T_FULL 2048
#define TT 128
#define NB_TOT 1025
#define KBANDS 36
#define EMBED 128
#define MAXF 130
#define FPAD 160
#define EPSV 1e-5f
#define LDS_W 84  // uint32 words per LDS row (336 B, 16B-aligned, bank-friendly)

typedef __attribute__((ext_vector_type(8))) short short8;
typedef __attribute__((ext_vector_type(4))) float floatx4;
typedef __attribute__((ext_vector_type(2))) float floatx2;

__device__ __forceinline__ void band_info(int band, int& nb, int& start) {
  if (band < 20)      { nb = 16; start = band << 4; }
  else if (band < 30) { nb = 32; start = 320 + ((band - 20) << 5); }
  else if (band < 35) { nb = 64; start = 640 + ((band - 30) << 6); }
  else                { nb = 65; start = 960; }
}

__device__ __forceinline__ unsigned short f2bf(float x) {
  union { float f; uint32_t u; } c; c.f = x;
  return (unsigned short)((c.u + 0x7FFFu + ((c.u >> 16) & 1u)) >> 16);
}

// ---- prologue: Wg = W*gamma (bf16, padded to FPAD with zeros),
//      S = sum_f Wg, BB = b + W.beta.  One wave per (band, e) row.
__global__ void __launch_bounds__(256) prep_kernel(
    const float* __restrict__ W, const float* __restrict__ gamma,
    const float* __restrict__ beta, const float* __restrict__ bvec,
    unsigned short* __restrict__ Wg, float* __restrict__ S, float* __restrict__ BB)
{
  int k = blockIdx.x;
  int w = threadIdx.x >> 6, lane = threadIdx.x & 63;
  int e = blockIdx.y * 4 + w;
  int nb, start; band_info(k, nb, start);
  int f = nb * 2;
  const float* wrow = W + ((size_t)k * EMBED + e) * MAXF;
  const float* grow = gamma + (size_t)k * MAXF;
  const float* brow = beta + (size_t)k * MAXF;
  unsigned short* orow = Wg + ((size_t)k * EMBED + e) * FPAD;

  float bb = 0.f;
  int i1 = lane, i2 = lane + 64, i3 = lane + 128;
  float v1 = 0.f, v2 = 0.f, v3 = 0.f;
  if (i1 < f) { float wv = wrow[i1]; v1 = wv * grow[i1]; bb += wv * brow[i1]; }
  if (i2 < f) { float wv = wrow[i2]; v2 = wv * grow[i2]; bb += wv * brow[i2]; }
  if (i3 < f) { float wv = wrow[i3]; v3 = wv * grow[i3]; bb += wv * brow[i3]; }
  orow[i1] = f2bf(v1);
  orow[i2] = f2bf(v2);
  if (i3 < FPAD) orow[i3] = f2bf(v3);
  float s = v1 + v2 + v3;
  #pragma unroll
  for (int off = 32; off > 0; off >>= 1) {
    s  += __shfl_down(s, off);
    bb += __shfl_down(bb, off);
  }
  if (lane == 0) {
    S[k * EMBED + e]  = s;
    BB[k * EMBED + e] = bvec[k * EMBED + e] + bb;
  }
}

// ---- main: per block = (b, band, 128-t tile).
// Stage x tile to LDS (bf16, swizzled), compute per-t LN stats,
// MFMA 128e x 128t, epilogue y = rstd*(G - mu*S) + BB.
__global__ void __launch_bounds__(256, 3) band_kernel(
    const float* __restrict__ spec, const unsigned short* __restrict__ Wg,
    const float* __restrict__ S, const float* __restrict__ BB,
    float* __restrict__ out)
{
  __shared__ uint32_t xn[TT * LDS_W];     // [t][word], word = (re,im) bf16 pair, XOR-swizzled
  __shared__ float part_s[4][64];
  __shared__ float part_q[4][64];
  __shared__ float mu_l[TT];
  __shared__ float rs_l[TT];

  int tid = threadIdx.x;
  int w = tid >> 6, lane = tid & 63;
  int band = blockIdx.y, b = blockIdx.z;
  int t0 = blockIdx.x * TT;
  int nb, start; band_info(band, nb, start);
  int f = nb * 2;
  int ksteps = (f + 31) >> 5;

  // ---- stage x tile (f x TT) into LDS as bf16, accumulate per-t stats.
  // wave w: bins j = (w>>1), (w>>1)+2, ... ; t-half = w&1. Lane owns one t.
  int tl = ((w & 1) << 6) | lane;          // local t 0..127
  int swz = (tl >> 3) & 3;
  const floatx2* sp = (const floatx2*)spec +
      ((size_t)(b * NB_TOT + start) * T_FULL + (t0 + tl));
  float s = 0.f, q = 0.f;
  for (int j = (w >> 1); j < nb; j += 2) {
    floatx2 v = sp[(size_t)j * T_FULL];
    float re = v.x, im = v.y;
    s += re + im;
    q += re * re + im * im;
    xn[tl * LDS_W + (j ^ (swz << 2))] =
        (uint32_t)f2bf(re) | ((uint32_t)f2bf(im) << 16);
  }
  if (f & 31) {  // band 35 only: zero cols f..160 (words 65..79), swizzled
    for (int idx = tid; idx < TT * 15; idx += 256) {
      int t = idx / 15, jz = 65 + idx % 15;
      xn[t * LDS_W + (jz ^ (((t >> 3) & 3) << 2))] = 0;
    }
  }
  part_s[w][lane] = s;
  part_q[w][lane] = q;
  __syncthreads();
  if (tid < TT) {
    int h = tid >> 6, li = tid & 63;
    float su = part_s[h][li] + part_s[h + 2][li];
    float sq = part_q[h][li] + part_q[h + 2][li];
    float inv_f = 1.0f / (float)f;
    float mu = su * inv_f;
    float var = sq * inv_f - mu * mu;
    mu_l[tid] = mu;
    rs_l[tid] = rsqrtf(var + EPSV);
  }
  __syncthreads();

  // ---- MFMA: G[e,t] = sum_k Wg[e,k] * x[k,t]; wave w owns e rows [32w, 32w+32)
  int lane16 = lane & 15, quad = lane >> 4;
  floatx4 acc[2][8];
  #pragma unroll
  for (int i = 0; i < 2; ++i)
    #pragma unroll
    for (int j = 0; j < 8; ++j) acc[i][j] = floatx4{0.f, 0.f, 0.f, 0.f};

  int ebase = w * 32;
  const unsigned short* wgb = Wg + ((size_t)band * EMBED + ebase) * FPAD;
  for (int kk = 0; kk < ksteps; ++kk) {
    // A-frag: A[m=lane16][k=quad*8+j], contiguous 16B from L2-hot Wg
    short8 a0 = *(const short8*)(wgb + (size_t)lane16 * FPAD + kk * 32 + quad * 8);
    short8 a1 = *(const short8*)(wgb + (size_t)(16 + lane16) * FPAD + kk * 32 + quad * 8);
    #pragma unroll
    for (int nt = 0; nt < 8; ++nt) {
      int t = nt * 16 + lane16;
      int blk = kk * 4 + (quad ^ ((t >> 3) & 3));          // un-swizzle
      short8 bfr = *(const short8*)&xn[t * LDS_W + blk * 4]; // ds_read_b128
      acc[0][nt] = __builtin_amdgcn_mfma_f32_16x16x32_bf16(a0, bfr, acc[0][nt], 0, 0, 0);
      acc[1][nt] = __builtin_amdgcn_mfma_f32_16x16x32_bf16(a1, bfr, acc[1][nt], 0, 0, 0);
    }
  }

  // ---- epilogue: y = rstd*(G - mu*S) + BB, store out[b][e][band][t]
  float muv[8], rsv[8];
  #pragma unroll
  for (int nt = 0; nt < 8; ++nt) {
    int t = nt * 16 + lane16;
    muv[nt] = mu_l[t];
    rsv[nt] = rs_l[t];
  }
  int obase = ((b * EMBED) * KBANDS + band) * T_FULL + t0;
  const float* Sb = S + band * EMBED + ebase;
  const float* Bb = BB + band * EMBED + ebase;
  #pragma unroll
  for (int et = 0; et < 2; ++et) {
    int e0 = et * 16 + quad * 4;
    floatx4 Sv = *(const floatx4*)(Sb + e0);
    floatx4 Bv = *(const floatx4*)(Bb + e0);
    #pragma unroll
    for (int nt = 0; nt < 8; ++nt) {
      int t = nt * 16 + lane16;
      #pragma unroll
      for (int r = 0; r < 4; ++r) {
        float y = rsv[nt] * (acc[et][nt][r] - muv[nt] * Sv[r]) + Bv[r];
        out[(size_t)obase + (size_t)(ebase + e0 + r) * (KBANDS * T_FULL) + t] = y;
      }
    }
  }
}

extern "C" void kernel_launch(void* const* d_in, const int* in_sizes, int n_in,
                              void* d_out, int out_size, void* d_ws, size_t ws_size,
                              hipStream_t stream) {
  const float* spec  = (const float*)d_in[0];
  const float* gamma = (const float*)d_in[1];
  const float* beta  = (const float*)d_in[2];
  const float* W     = (const float*)d_in[3];
  const float* bvec  = (const float*)d_in[4];
  float* out = (float*)d_out;

  // ws layout: Wg bf16 [36][128][160] (1,474,560 B) | S [36*128] f32 | BB [36*128] f32
  unsigned short* Wg = (unsigned short*)d_ws;
  size_t wg_bytes = (size_t)KBANDS * EMBED * FPAD * sizeof(unsigned short);
  float* S  = (float*)((char*)d_ws + wg_bytes);
  float* BB = S + KBANDS * EMBED;

  prep_kernel<<<dim3(KBANDS, 32), dim3(256), 0, stream>>>(W, gamma, beta, bvec, Wg, S, BB);
  band_kernel<<<dim3(T_FULL / TT, KBANDS, 8), dim3(256), 0, stream>>>(spec, Wg, S, BB, out);
}